// Round 12
// baseline (382.581 us; speedup 1.0000x reference)
//
#include <hip/hip_runtime.h>
#include <hip/hip_bf16.h>
#include <cstdint>

#define T_TOK 4096
#define DMODEL 1024
#define HDIM 2048

typedef short bf16x8 __attribute__((ext_vector_type(8)));
typedef float f32x4 __attribute__((ext_vector_type(4)));
typedef uint32_t u32x4 __attribute__((ext_vector_type(4)));

#define WAITVM(N) asm volatile("s_waitcnt vmcnt(" #N ")" ::: "memory")
#define BARX() asm volatile("s_barrier" ::: "memory")

__device__ __forceinline__ uint32_t cvt_pk_bf16(float lo, float hi) {
  uint32_t d;
  asm("v_cvt_pk_bf16_f32 %0, %1, %2" : "=v"(d) : "v"(lo), "v"(hi));
  return d;
}
__device__ __forceinline__ unsigned short f2bf(float f) {
  uint32_t d;
  asm("v_cvt_pk_bf16_f32 %0, %1, %1" : "=v"(d) : "v"(f));
  return (unsigned short)d;
}
__device__ __forceinline__ float bf2f(unsigned short u) {
  return __uint_as_float((uint32_t)u << 16);
}
// fast exact-erf GELU: Abramowitz-Stegun 7.1.26, |err| <= 1.5e-7
__device__ __forceinline__ float gelu_fast(float v) {
  float z = v * 0.70710678118654752f;
  float az = fabsf(z);
  float t = __frcp_rn(1.0f + 0.3275911f * az);
  float poly = ((((1.061405429f * t - 1.453152027f) * t + 1.421413741f) * t
                 - 0.284496736f) * t + 0.254829592f) * t;
  float er = 1.0f - poly * __expf(-z * z);
  er = (z < 0.f) ? -er : er;
  return 0.5f * v * (1.0f + er);
}
__device__ __forceinline__ void gload16(const void* g, void* lds) {
  __builtin_amdgcn_global_load_lds((const __attribute__((address_space(1))) void*)g,
                                   (__attribute__((address_space(3))) void*)lds, 16, 0, 0);
}
// bijective XCD-chunked remap (m204)
__device__ __forceinline__ int xcd_remap(int d, int nblk) {
  int q = nblk >> 3, r = nblk & 7, xc = d & 7, i = d >> 3;
  return (xc < r ? xc * (q + 1) : r * (q + 1) + (xc - r) * q) + i;
}

#define LSTR 1032  // LDS row stride (shorts): 2064 B, 16B-aligned, banks spread

// ========== convert: standalone 512-thread LDS-transpose (full occupancy) ======
// Blocks 0..2303:    wB panels (e*256+nf): 16 rows x 1024 cols of w1/w3
// Blocks 2304..3455: wd panels (d16,half): 16 rows x 1024 cols of w2
// wB per expert: [nf:256][k32:32][lane:64][8]   wd per expert: [d16:64][h32:64][lane:64][8]
__global__ __launch_bounds__(512) void convert_kernel(
    const float* __restrict__ w1, const float* __restrict__ w3,
    const float* __restrict__ w1s, const float* __restrict__ w3s,
    const float* __restrict__ w2, const float* __restrict__ w2s,
    short* __restrict__ wB, short* __restrict__ wd) {
  __shared__ short smem[16 * LSTR];  // 33024 B -> 4 blocks/CU x 8 waves = full occ
  int bid = blockIdx.x, tid = threadIdx.x;

  const float* src;
  short* dst;
  size_t rstride;
  if (bid < 2304) {
    int e = bid >> 8, nf = bid & 255;
    size_t so = (size_t)((nf >> 1) * 16) * DMODEL;
    src = (nf & 1) ? ((e < 8) ? w3 + (size_t)e * 2097152 + so : w3s + so)
                   : ((e < 8) ? w1 + (size_t)e * 2097152 + so : w1s + so);
    dst = wB + (size_t)e * 4194304 + (size_t)nf * 16384;
    rstride = DMODEL;
  } else {
    int c2 = bid - 2304;
    int e = c2 >> 7, rem = c2 & 127, d16 = rem >> 1, half = rem & 1;
    src = ((e < 8) ? w2 + (size_t)e * 2097152 : w2s) +
          (size_t)(d16 * 16) * HDIM + half * 1024;
    dst = wd + (size_t)e * 2097152 + ((size_t)d16 * 64 + half * 32) * 512;
    rstride = HDIM;
  }
  // phase 1: fully-coalesced row reads -> bf16 -> LDS (8 float4 per thread)
#pragma unroll
  for (int it = 0; it < 8; ++it) {
    int flat = it * 512 + tid;           // 0..4095 (16 rows x 256 float4)
    int p = flat >> 8, c4 = flat & 255;
    float4 v = *(const float4*)(src + (size_t)p * rstride + c4 * 4);
    uint2 pk = {cvt_pk_bf16(v.x, v.y), cvt_pk_bf16(v.z, v.w)};
    *(uint2*)&smem[p * LSTR + c4 * 4] = pk;
  }
  __syncthreads();
  // phase 2: fragment-order LDS reads -> contiguous global writes (4 per thread)
#pragma unroll
  for (int it = 0; it < 4; ++it) {
    int flat = it * 512 + tid;           // 0..2047 (32 k32 x 64 lanes)
    int k32 = flat >> 6, ln = flat & 63;
    bf16x8 v = *(const bf16x8*)&smem[(ln & 15) * LSTR + k32 * 32 + (ln >> 4) * 8];
    *(bf16x8*)&dst[(size_t)flat * 8] = v;
  }
}

// ---------------- router: one wave per token; also emits xb + token routing ------
__global__ __launch_bounds__(256) void router_kernel(
    const float* __restrict__ x, const float* __restrict__ Wr,
    int* __restrict__ cursor, int* __restrict__ cnt1,
    float* __restrict__ psum, int* __restrict__ perm,
    int* __restrict__ tokpos, float* __restrict__ wtok,
    short* __restrict__ xb) {
  __shared__ float4 sW[8 * 256];
  __shared__ float sP[8];
  int tid = threadIdx.x;
  const float4* W4 = (const float4*)Wr;
  for (int i = tid; i < 2048; i += 256) sW[i] = W4[i];
  if (tid < 8) sP[tid] = 0.f;
  __syncthreads();

  int lane = tid & 63, wid = tid >> 6;
  int t = blockIdx.x * 4 + wid;
  float acc[8] = {0.f, 0.f, 0.f, 0.f, 0.f, 0.f, 0.f, 0.f};
  const float4* x4 = (const float4*)(x + (size_t)t * DMODEL);
#pragma unroll
  for (int it = 0; it < 4; ++it) {
    float4 xv = x4[it * 64 + lane];
    uint2 pk = {cvt_pk_bf16(xv.x, xv.y), cvt_pk_bf16(xv.z, xv.w)};
    *(uint2*)(xb + (size_t)t * DMODEL + it * 256 + lane * 4) = pk;
#pragma unroll
    for (int e = 0; e < 8; ++e) {
      float4 wv = sW[e * 256 + it * 64 + lane];
      acc[e] += xv.x * wv.x + xv.y * wv.y + xv.z * wv.z + xv.w * wv.w;
    }
  }
#pragma unroll
  for (int e = 0; e < 8; ++e)
    for (int off = 32; off; off >>= 1) acc[e] += __shfl_xor(acc[e], off);

  float mx = acc[0];
#pragma unroll
  for (int e = 1; e < 8; ++e) mx = fmaxf(mx, acc[e]);
  float ex[8], s = 0.f;
#pragma unroll
  for (int e = 0; e < 8; ++e) { ex[e] = expf(acc[e] - mx); s += ex[e]; }
  float inv = 1.f / s;
  int e0 = 0;
#pragma unroll
  for (int e = 1; e < 8; ++e) if (acc[e] > acc[e0]) e0 = e;
  int e1 = (e0 == 0) ? 1 : 0;
#pragma unroll
  for (int e = 0; e < 8; ++e) if (e != e0 && acc[e] > acc[e1]) e1 = e;

  if (lane == 0) {
#pragma unroll
    for (int e = 0; e < 8; ++e) atomicAdd(&sP[e], ex[e] * inv);
    atomicAdd(&cnt1[e0], 1);
    int s0 = atomicAdd(&cursor[e0], 1);
    perm[e0 * 4096 + s0] = t;
    int s1 = atomicAdd(&cursor[e1], 1);
    perm[e1 * 4096 + s1] = t;
    tokpos[2 * t] = (e0 << 12) | s0;
    tokpos[2 * t + 1] = (e1 << 12) | s1;
    wtok[2 * t] = ex[e0] * inv;
    wtok[2 * t + 1] = ex[e1] * inv;
  }
  __syncthreads();
  if (tid < 8) atomicAdd(&psum[tid], sP[tid]);
}

// ------- finalize: 256-aligned bases + work128 + work256 + aux loss -------
__global__ void finalize_kernel(const int* __restrict__ cursor,
                                const int* __restrict__ cnt1,
                                const float* __restrict__ psum,
                                int* __restrict__ base,
                                int* __restrict__ work128, int* __restrict__ n128,
                                int* __restrict__ work256, int* __restrict__ n256,
                                float* __restrict__ aux_out) {
  if (threadIdx.x == 0) {
    int b = 0, a1 = 0, a2 = 0;
    for (int e = 0; e < 9; ++e) {
      int c = (e < 8) ? cursor[e] : 4096;
      base[e] = b;
      int t1 = (c + 127) >> 7;
      for (int mt = 0; mt < t1; ++mt) work128[a1++] = (e << 8) | mt;
      int t2 = (c + 255) >> 8;
      for (int mt = 0; mt < t2; ++mt) work256[a2++] = (e << 8) | mt;
      b += t2 << 8;
    }
    *n128 = a1; *n256 = a2;
    float aux = 0.f;
    for (int e = 0; e < 8; ++e)
      aux += ((float)cnt1[e] * (1.f / T_TOK)) * (psum[e] * (1.f / T_TOK));
    aux_out[0] = 0.01f * 8.f * aux;
  }
}

// ===== up+gate GEMM: 128x128, 4 waves, wave-tile 64x64, BK=32, dbuf 32KB =====
__global__ __launch_bounds__(256, 4) void gemm_upgate(
    const short* __restrict__ xb, const short* __restrict__ wB,
    const int* __restrict__ cursor, const int* __restrict__ base,
    const int* __restrict__ work, const int* __restrict__ nwork,
    const int* __restrict__ perm, unsigned short* __restrict__ hbuf) {
  int nblk = *nwork * 32;
  int d = blockIdx.x;
  if (d >= nblk) return;
  int o = xcd_remap(d, nblk);
  int y = o >> 5, nt = o & 31;
  int wk = work[y];
  int e = wk >> 8, mt = wk & 255;
  int cnt = (e < 8) ? cursor[e] : 4096;
  int hb = base[e];
  const short* wE = wB + (size_t)e * 4194304;

  __shared__ short lds[16384];

  int tid = threadIdx.x, lane = tid & 63, wid = tid >> 6;
  int fr = lane & 15, q4r = lane >> 4;
  int wm = wid >> 1, wn = wid & 1;

  size_t aOff[2], bOff[2];
#pragma unroll
  for (int c = 0; c < 2; ++c) {
    int g = c * 4 + wid;
    int slot = mt * 128 + g * 16 + fr;
    int tok = (e == 8) ? slot : ((slot < cnt) ? perm[e * 4096 + slot] : 0);
    aOff[c] = (size_t)tok * DMODEL + q4r * 8;
    bOff[c] = (size_t)(nt * 8 + g) * 32 * 512 + lane * 8;
  }

  auto stage = [&](int b, int t) {
#pragma unroll
    for (int c = 0; c < 2; ++c) {
      int g = c * 4 + wid;
      gload16(xb + aOff[c] + t * 32, &lds[b * 8192 + g * 512 + lane * 8]);
      gload16(wE + bOff[c] + (size_t)t * 512,
              &lds[b * 8192 + 4096 + g * 512 + lane * 8]);
    }
  };

  f32x4 acc[4][4] = {};

  auto compute = [&](int b) {
    bf16x8 af[4], bf[4];
#pragma unroll
    for (int m = 0; m < 4; ++m)
      af[m] = *(const bf16x8*)&lds[b * 8192 + (wm * 4 + m) * 512 + lane * 8];
#pragma unroll
    for (int n = 0; n < 4; ++n)
      bf[n] = *(const bf16x8*)&lds[b * 8192 + 4096 + (wn * 4 + n) * 512 + lane * 8];
    __builtin_amdgcn_s_setprio(1);
#pragma unroll
    for (int m = 0; m < 4; ++m)
#pragma unroll
      for (int n = 0; n < 4; ++n)
        acc[m][n] = __builtin_amdgcn_mfma_f32_16x16x32_bf16(af[m], bf[n], acc[m][n], 0, 0, 0);
    __builtin_amdgcn_s_setprio(0);
  };

  stage(0, 0);
  __syncthreads();
  int b = 0;
#pragma unroll 1
  for (int t = 0; t < 32; ++t) {
    if (t < 31) stage(b ^ 1, t + 1);
    compute(b);
    __syncthreads();
    b ^= 1;
  }

  // epilogue: pair even/odd n-frags (u, g) -> gelu(u)*g
#pragma unroll
  for (int m = 0; m < 4; ++m) {
#pragma unroll
    for (int p = 0; p < 2; ++p) {
      f32x4 u = acc[m][2 * p], g = acc[m][2 * p + 1];
      int hcol = (nt * 4 + wn * 2 + p) * 16 + fr;
#pragma unroll
      for (int j = 0; j < 4; ++j) {
        int sl = mt * 128 + wm * 64 + m * 16 + q4r * 4 + j;
        float hv = (sl < cnt) ? gelu_fast(u[j]) * g[j] : 0.f;
        hbuf[(size_t)(hb + sl) * HDIM + hcol] = f2bf(hv);
      }
    }
  }
}

// ============ down GEMM: 256x256, 4-phase counted-vmcnt pipeline ==========
__global__ __launch_bounds__(512) void gemm_down8(
    const unsigned short* __restrict__ hbuf, const short* __restrict__ wd,
    const int* __restrict__ base,
    const int* __restrict__ work, const int* __restrict__ nwork,
    unsigned short* __restrict__ yb) {
  int y = blockIdx.y;
  if (y >= *nwork) return;
  int wk = work[y];
  int e = wk >> 8, mt = wk & 255, nt = blockIdx.x;
  int hb = base[e];
  const short* wdE = wd + (size_t)e * 2097152;

  __shared__ short lds[65536];

  int tid = threadIdx.x, lane = tid & 63, wid = tid >> 6;
  int wm = wid >> 2, wn = wid & 3;
  int fr = lane & 15, q4r = lane >> 4;

  size_t aOff[2];
#pragma unroll
  for (int c = 0; c < 2; ++c)
    aOff[c] = (size_t)(hb + mt * 256 + (c * 8 + wid) * 16 + fr) * HDIM + q4r * 8;
  size_t bOff[2];
#pragma unroll
  for (int c = 0; c < 2; ++c)
    bOff[c] = ((size_t)(nt * 16 + c * 8 + wid) * 64) * 512 + lane * 8;

#define DWN_STAGE_A(tt, k32)                                                   \
  { int bb_ = ((tt) & 1) * 32768;                                              \
    gload16(hbuf + aOff[0] + (tt) * 64 + (k32) * 32,                           \
            &lds[bb_ + ((k32) * 16 + wid) * 512 + lane * 8]);                  \
    gload16(hbuf + aOff[1] + (tt) * 64 + (k32) * 32,                           \
            &lds[bb_ + ((k32) * 16 + 8 + wid) * 512 + lane * 8]); }
#define DWN_STAGE_B(tt, k32)                                                   \
  { int bb_ = ((tt) & 1) * 32768;                                              \
    gload16(wdE + bOff[0] + (size_t)((tt) * 2 + (k32)) * 512,                  \
            &lds[bb_ + 16384 + ((k32) * 16 + wid) * 512 + lane * 8]);          \
    gload16(wdE + bOff[1] + (size_t)((tt) * 2 + (k32)) * 512,                  \
            &lds[bb_ + 16384 + ((k32) * 16 + 8 + wid) * 512 + lane * 8]); }
#define DWN_READA(k32, mh)                                                     \
  { _Pragma("unroll") for (int i = 0; i < 4; ++i)                              \
      af[i] = *(const bf16x8*)&lds[bb + ((k32) * 16 + wm * 8 + (mh) * 4 + i) * \
                                       512 + lane * 8]; }
#define DWN_READB(k32)                                                         \
  { _Pragma("unroll") for (int n = 0; n < 4; ++n)                              \
      bf[n] = *(const bf16x8*)&lds[bb + 16384 + ((k32) * 16 + wn * 4 + n) *    \
                                       512 + lane * 8]; }
#define DWN_MFMA(mh)                                                           \
  { __builtin_amdgcn_s_setprio(1);                                             \
    _Pragma("unroll") for (int i = 0; i < 4; ++i)                              \
      _Pragma("unroll") for (int n = 0; n < 4; ++n)                            \
        acc[(mh) * 4 + i][n] = __builtin_amdgcn_mfma_f32_16x16x32_bf16(        \
            af[i], bf[n], acc[(mh) * 4 + i][n], 0, 0, 0);                      \
    __builtin_amdgcn_s_setprio(0); }

  f32x4 acc[8][4] = {};
  bf16x8 af[4], bf[4];

  DWN_STAGE_A(0, 0); DWN_STAGE_B(0, 0); DWN_STAGE_A(0, 1); DWN_STAGE_B(0, 1);
  WAITVM(4); BARX();

#pragma unroll 1
  for (int t = 0; t < 31; ++t) {
    const int bb = (t & 1) * 32768;
    DWN_READA(0, 0); DWN_READB(0); DWN_STAGE_A(t + 1, 0);
    BARX(); DWN_MFMA(0); BARX();
    DWN_READA(0, 1); DWN_STAGE_B(t + 1, 0);
    BARX(); DWN_MFMA(1); WAITVM(4); BARX();
    DWN_READA(1, 0); DWN_READB(1); DWN_STAGE_A(t + 1, 1);
    BARX(); DWN_MFMA(0); BARX();
    DWN_READA(1, 1); DWN_STAGE_B(t + 1, 1);
    BARX(); DWN_MFMA(1); WAITVM(4); BARX();
  }
  {  // t = 31
    const int bb = 32768;
    DWN_READA(0, 0); DWN_READB(0); BARX(); DWN_MFMA(0); BARX();
    DWN_READA(0, 1); BARX(); DWN_MFMA(1); WAITVM(0); BARX();
    DWN_READA(1, 0); DWN_READB(1); BARX(); DWN_MFMA(0); BARX();
    DWN_READA(1, 1); DWN_MFMA(1);
  }

#pragma unroll
  for (int m = 0; m < 8; ++m) {
#pragma unroll
    for (int n = 0; n < 4; ++n) {
      int col = (nt * 16 + wn * 4 + n) * 16 + fr;
      f32x4 a = acc[m][n];
#pragma unroll
      for (int j = 0; j < 4; ++j) {
        int row = mt * 256 + wm * 128 + m * 16 + q4r * 4 + j;
        yb[(size_t)(hb + row) * DMODEL + col] = f2bf(a[j]);
      }
    }
  }
}

// ------------ gather: out[t] = w0*y[p0] + w1*y[p1] + y[shared+t] ------------
__global__ __launch_bounds__(256) void gather_kernel(
    const unsigned short* __restrict__ yb, const int* __restrict__ tokpos,
    const float* __restrict__ wtok, const int* __restrict__ base,
    float* __restrict__ out) {
  int t = blockIdx.x, c4 = threadIdx.x;
  int p0 = tokpos[2 * t], p1 = tokpos[2 * t + 1];
  float w0 = wtok[2 * t], w1 = wtok[2 * t + 1];
  size_t r0 = (size_t)(base[p0 >> 12] + (p0 & 4095)) * DMODEL;
  size_t r1 = (size_t)(base[p1 >> 12] + (p1 & 4095)) * DMODEL;
  size_t rs = (size_t)(base[8] + t) * DMODEL;
  ushort4 v0 = *(const ushort4*)(yb + r0 + c4 * 4);
  ushort4 v1 = *(const ushort4*)(yb + r1 + c4 * 4);
  ushort4 vs = *(const ushort4*)(yb + rs + c4 * 4);
  float4 o;
  o.x = w0 * bf2f(v0.x) + w1 * bf2f(v1.x) + bf2f(vs.x);
  o.y = w0 * bf2f(v0.y) + w1 * bf2f(v1.y) + bf2f(vs.y);
  o.z = w0 * bf2f(v0.z) + w1 * bf2f(v1.z) + bf2f(vs.z);
  o.w = w0 * bf2f(v0.w) + w1 * bf2f(v1.w) + bf2f(vs.w);
  *(float4*)(out + (size_t)t * DMODEL + c4 * 4) = o;
}

extern "C" void kernel_launch(void* const* d_in, const int* in_sizes, int n_in,
                              void* d_out, int out_size, void* d_ws, size_t ws_size,
                              hipStream_t stream) {
  const float* x   = (const float*)d_in[0];
  const float* Wr  = (const float*)d_in[1];
  const float* w1  = (const float*)d_in[2];
  const float* w2  = (const float*)d_in[3];
  const float* w3  = (const float*)d_in[4];
  const float* w1s = (const float*)d_in[5];
  const float* w2s = (const float*)d_in[6];
  const float* w3s = (const float*)d_in[7];
  float* out = (float*)d_out;

  char* ws = (char*)d_ws;
  const size_t HBUF_OFF = 0;                        // 14336*2048 bf16 = 58.7 MB
  const size_t XB_OFF   = 58720256;                 // 4096*1024 bf16
  const size_t WB_OFF   = XB_OFF + 8388608;         // 9*4M shorts = 75.5 MB
  const size_t WD_OFF   = WB_OFF + 75497472;        // 9*2M shorts = 37.7 MB
  const size_t PERM_OFF = WD_OFF + 37748736;        // 8*4096 int
  const size_t TP_OFF   = PERM_OFF + 131072;        // 8192 int
  const size_t WT_OFF   = TP_OFF + 32768;           // 8192 float
  const size_t CTRL_OFF = WT_OFF + 32768;           // 256 B
  const size_t W128_OFF = CTRL_OFF + 256;           // 128 ints
  const size_t W256_OFF = W128_OFF + 512;           // 64 ints

  unsigned short* hbuf = (unsigned short*)(ws + HBUF_OFF);
  short* xb = (short*)(ws + XB_OFF);
  short* wB = (short*)(ws + WB_OFF);
  short* wd = (short*)(ws + WD_OFF);
  unsigned short* yb = (unsigned short*)(ws + WB_OFF);  // overlays wB (dead after upgate)
  int*   perm   = (int*)(ws + PERM_OFF);
  int*   tokpos = (int*)(ws + TP_OFF);
  float* wtok   = (float*)(ws + WT_OFF);
  int*   cursor = (int*)(ws + CTRL_OFF);
  int*   cnt1   = (int*)(ws + CTRL_OFF + 64);
  float* psum   = (float*)(ws + CTRL_OFF + 128);
  int*   base   = (int*)(ws + CTRL_OFF + 192);
  int*   n128   = (int*)(ws + CTRL_OFF + 236);
  int*   n256   = (int*)(ws + CTRL_OFF + 240);
  int*   work128 = (int*)(ws + W128_OFF);
  int*   work256 = (int*)(ws + W256_OFF);

  hipMemsetAsync(ws + CTRL_OFF, 0, 256, stream);

  router_kernel<<<1024, 256, 0, stream>>>(x, Wr, cursor, cnt1, psum, perm,
                                          tokpos, wtok, xb);
  convert_kernel<<<3456, 512, 0, stream>>>(w1, w3, w1s, w3s, w2, w2s, wB, wd);
  finalize_kernel<<<1, 64, 0, stream>>>(cursor, cnt1, psum, base,
                                        work128, n128, work256, n256,
                                        out + (size_t)T_TOK * DMODEL);
  gemm_upgate<<<3328, 256, 0, stream>>>(xb, wB, cursor, base, work128, n128,
                                        perm, hbuf);
  gemm_down8<<<dim3(4, 64), 512, 0, stream>>>(hbuf, wd, base, work256, n256, yb);
  gather_kernel<<<4096, 256, 0, stream>>>(yb, tokpos, wtok, base, out);
}

// Round 13
// 372.153 us; speedup vs baseline: 1.0280x; 1.0280x over previous
//
#include <hip/hip_runtime.h>
#include <hip/hip_bf16.h>
#include <cstdint>

#define T_TOK 4096
#define DMODEL 1024
#define HDIM 2048

typedef short bf16x8 __attribute__((ext_vector_type(8)));
typedef float f32x4 __attribute__((ext_vector_type(4)));
typedef uint32_t u32x4 __attribute__((ext_vector_type(4)));

#define WAITVM(N) asm volatile("s_waitcnt vmcnt(" #N ")" ::: "memory")
#define BARX() asm volatile("s_barrier" ::: "memory")

__device__ __forceinline__ uint32_t cvt_pk_bf16(float lo, float hi) {
  uint32_t d;
  asm("v_cvt_pk_bf16_f32 %0, %1, %2" : "=v"(d) : "v"(lo), "v"(hi));
  return d;
}
__device__ __forceinline__ unsigned short f2bf(float f) {
  uint32_t d;
  asm("v_cvt_pk_bf16_f32 %0, %1, %1" : "=v"(d) : "v"(f));
  return (unsigned short)d;
}
__device__ __forceinline__ float bf2f(unsigned short u) {
  return __uint_as_float((uint32_t)u << 16);
}
// fast exact-erf GELU: Abramowitz-Stegun 7.1.26, |err| <= 1.5e-7
__device__ __forceinline__ float gelu_fast(float v) {
  float z = v * 0.70710678118654752f;
  float az = fabsf(z);
  float t = __frcp_rn(1.0f + 0.3275911f * az);
  float poly = ((((1.061405429f * t - 1.453152027f) * t + 1.421413741f) * t
                 - 0.284496736f) * t + 0.254829592f) * t;
  float er = 1.0f - poly * __expf(-z * z);
  er = (z < 0.f) ? -er : er;
  return 0.5f * v * (1.0f + er);
}
__device__ __forceinline__ void gload16(const void* g, void* lds) {
  __builtin_amdgcn_global_load_lds((const __attribute__((address_space(1))) void*)g,
                                   (__attribute__((address_space(3))) void*)lds, 16, 0, 0);
}
__device__ __forceinline__ u32x4 pk8(const float* s) {
  float4 v0 = ((const float4*)s)[0], v1 = ((const float4*)s)[1];
  u32x4 p = {cvt_pk_bf16(v0.x, v0.y), cvt_pk_bf16(v0.z, v0.w),
             cvt_pk_bf16(v1.x, v1.y), cvt_pk_bf16(v1.z, v1.w)};
  return p;
}
// bijective XCD-chunked remap (m204)
__device__ __forceinline__ int xcd_remap(int d, int nblk) {
  int q = nblk >> 3, r = nblk & 7, xc = d & 7, i = d >> 3;
  return (xc < r ? xc * (q + 1) : r * (q + 1) + (xc - r) * q) + i;
}

// ========== prep1: wB-convert (blocks 0..18431, no LDS) + router (no-LDS Wr) ==
// wB per expert (u/g col-interleaved): [nf:256][k32:32][lane:64][8]
__global__ __launch_bounds__(256) void prep1_kernel(
    const float* __restrict__ x, const float* __restrict__ Wr,
    const float* __restrict__ w1, const float* __restrict__ w3,
    const float* __restrict__ w1s, const float* __restrict__ w3s,
    short* __restrict__ wB,
    int* __restrict__ cursor, int* __restrict__ cnt1,
    float* __restrict__ psum, int* __restrict__ perm,
    int* __restrict__ tokpos, float* __restrict__ wtok,
    short* __restrict__ xb) {
  __shared__ float sP[8];
  int bid = blockIdx.x, tid = threadIdx.x;

  if (bid < 18432) {  // ---- wB convert (gather-style, full occupancy) ----
    int id = bid * 256 + tid;
    int e = id >> 19, rem = id & 524287;
    int nf = rem >> 11, k32 = (rem >> 6) & 31, ln = rem & 63;
    int h = (nf >> 1) * 16 + (ln & 15);
    size_t so = (size_t)h * DMODEL + k32 * 32 + (ln >> 4) * 8;
    const float* src = (nf & 1)
        ? ((e < 8) ? w3 + (size_t)e * 2097152 + so : w3s + so)
        : ((e < 8) ? w1 + (size_t)e * 2097152 + so : w1s + so);
    *(u32x4*)(wB + (size_t)id * 8) = pk8(src);
    return;
  }

  // ---- router: Wr read direct from global (L2-hot, 32 KB) ----
  if (tid < 8) sP[tid] = 0.f;
  __syncthreads();

  int lane = tid & 63, wid = tid >> 6;
  int t = (bid - 18432) * 4 + wid;
  float acc[8] = {0.f, 0.f, 0.f, 0.f, 0.f, 0.f, 0.f, 0.f};
  const float4* x4 = (const float4*)(x + (size_t)t * DMODEL);
  const float4* W4 = (const float4*)Wr;
#pragma unroll
  for (int it = 0; it < 4; ++it) {
    float4 xv = x4[it * 64 + lane];
    uint2 pk = {cvt_pk_bf16(xv.x, xv.y), cvt_pk_bf16(xv.z, xv.w)};
    *(uint2*)(xb + (size_t)t * DMODEL + it * 256 + lane * 4) = pk;
#pragma unroll
    for (int e = 0; e < 8; ++e) {
      float4 wv = W4[e * 256 + it * 64 + lane];
      acc[e] += xv.x * wv.x + xv.y * wv.y + xv.z * wv.z + xv.w * wv.w;
    }
  }
#pragma unroll
  for (int e = 0; e < 8; ++e)
    for (int off = 32; off; off >>= 1) acc[e] += __shfl_xor(acc[e], off);

  float mx = acc[0];
#pragma unroll
  for (int e = 1; e < 8; ++e) mx = fmaxf(mx, acc[e]);
  float ex[8], s = 0.f;
#pragma unroll
  for (int e = 0; e < 8; ++e) { ex[e] = expf(acc[e] - mx); s += ex[e]; }
  float inv = 1.f / s;
  int e0 = 0;
#pragma unroll
  for (int e = 1; e < 8; ++e) if (acc[e] > acc[e0]) e0 = e;
  int e1 = (e0 == 0) ? 1 : 0;
#pragma unroll
  for (int e = 0; e < 8; ++e) if (e != e0 && acc[e] > acc[e1]) e1 = e;

  if (lane == 0) {
#pragma unroll
    for (int e = 0; e < 8; ++e) atomicAdd(&sP[e], ex[e] * inv);
    atomicAdd(&cnt1[e0], 1);
    int s0 = atomicAdd(&cursor[e0], 1);
    perm[e0 * 4096 + s0] = t;
    int s1 = atomicAdd(&cursor[e1], 1);
    perm[e1 * 4096 + s1] = t;
    tokpos[2 * t] = (e0 << 12) | s0;
    tokpos[2 * t + 1] = (e1 << 12) | s1;
    wtok[2 * t] = ex[e0] * inv;
    wtok[2 * t + 1] = ex[e1] * inv;
  }
  __syncthreads();
  if (tid < 8) atomicAdd(&psum[tid], sP[tid]);
}

// ------- finalize: 256-aligned bases + work128 + work256 + aux loss -------
__global__ void finalize_kernel(const int* __restrict__ cursor,
                                const int* __restrict__ cnt1,
                                const float* __restrict__ psum,
                                int* __restrict__ base,
                                int* __restrict__ work128, int* __restrict__ n128,
                                int* __restrict__ work256, int* __restrict__ n256,
                                float* __restrict__ aux_out) {
  if (threadIdx.x == 0) {
    int b = 0, a1 = 0, a2 = 0;
    for (int e = 0; e < 9; ++e) {
      int c = (e < 8) ? cursor[e] : 4096;
      base[e] = b;
      int t1 = (c + 127) >> 7;
      for (int mt = 0; mt < t1; ++mt) work128[a1++] = (e << 8) | mt;
      int t2 = (c + 255) >> 8;
      for (int mt = 0; mt < t2; ++mt) work256[a2++] = (e << 8) | mt;
      b += t2 << 8;
    }
    *n128 = a1; *n256 = a2;
    float aux = 0.f;
    for (int e = 0; e < 8; ++e)
      aux += ((float)cnt1[e] * (1.f / T_TOK)) * (psum[e] * (1.f / T_TOK));
    aux_out[0] = 0.01f * 8.f * aux;
  }
}

// ===== fused: up+gate GEMM (blocks 0..3327) + wd-convert filler (rest) =====
// upgate: 128x128, 4 waves, wave-tile 64x64, BK=32, dbuf 32KB.
// wd per expert: [d16:64][h32:64][lane:64][8]  (read only by gemm_down8 later)
__global__ __launch_bounds__(256, 4) void gemm_upgate_f(
    const short* __restrict__ xb, const short* __restrict__ wB,
    const float* __restrict__ w2, const float* __restrict__ w2s,
    short* __restrict__ wd,
    const int* __restrict__ cursor, const int* __restrict__ base,
    const int* __restrict__ work, const int* __restrict__ nwork,
    const int* __restrict__ perm, unsigned short* __restrict__ hbuf) {
  __shared__ short lds[16384];

  if (blockIdx.x >= 3328) {  // ---- wd convert filler ----
    int id = (blockIdx.x - 3328) * 256 + threadIdx.x;
    int e = id >> 18, rem = id & 262143;
    int d16 = rem >> 12, h32 = (rem >> 6) & 63, ln = rem & 63;
    size_t so = (size_t)(d16 * 16 + (ln & 15)) * HDIM + h32 * 32 + (ln >> 4) * 8;
    const float* s2 = (e < 8) ? w2 + (size_t)e * 2097152 + so : w2s + so;
    *(u32x4*)(wd + (size_t)id * 8) = pk8(s2);
    return;
  }

  int nblk = *nwork * 32;
  int d = blockIdx.x;
  if (d >= nblk) return;
  int o = xcd_remap(d, nblk);
  int y = o >> 5, nt = o & 31;
  int wk = work[y];
  int e = wk >> 8, mt = wk & 255;
  int cnt = (e < 8) ? cursor[e] : 4096;
  int hb = base[e];
  const short* wE = wB + (size_t)e * 4194304;

  int tid = threadIdx.x, lane = tid & 63, wid = tid >> 6;
  int fr = lane & 15, q4r = lane >> 4;
  int wm = wid >> 1, wn = wid & 1;

  size_t aOff[2], bOff[2];
#pragma unroll
  for (int c = 0; c < 2; ++c) {
    int g = c * 4 + wid;
    int slot = mt * 128 + g * 16 + fr;
    int tok = (e == 8) ? slot : ((slot < cnt) ? perm[e * 4096 + slot] : 0);
    aOff[c] = (size_t)tok * DMODEL + q4r * 8;
    bOff[c] = (size_t)(nt * 8 + g) * 32 * 512 + lane * 8;
  }

  auto stage = [&](int b, int t) {
#pragma unroll
    for (int c = 0; c < 2; ++c) {
      int g = c * 4 + wid;
      gload16(xb + aOff[c] + t * 32, &lds[b * 8192 + g * 512 + lane * 8]);
      gload16(wE + bOff[c] + (size_t)t * 512,
              &lds[b * 8192 + 4096 + g * 512 + lane * 8]);
    }
  };

  f32x4 acc[4][4] = {};

  auto compute = [&](int b) {
    bf16x8 af[4], bf[4];
#pragma unroll
    for (int m = 0; m < 4; ++m)
      af[m] = *(const bf16x8*)&lds[b * 8192 + (wm * 4 + m) * 512 + lane * 8];
#pragma unroll
    for (int n = 0; n < 4; ++n)
      bf[n] = *(const bf16x8*)&lds[b * 8192 + 4096 + (wn * 4 + n) * 512 + lane * 8];
    __builtin_amdgcn_s_setprio(1);
#pragma unroll
    for (int m = 0; m < 4; ++m)
#pragma unroll
      for (int n = 0; n < 4; ++n)
        acc[m][n] = __builtin_amdgcn_mfma_f32_16x16x32_bf16(af[m], bf[n], acc[m][n], 0, 0, 0);
    __builtin_amdgcn_s_setprio(0);
  };

  stage(0, 0);
  __syncthreads();
  int b = 0;
#pragma unroll 1
  for (int t = 0; t < 32; ++t) {
    if (t < 31) stage(b ^ 1, t + 1);
    compute(b);
    __syncthreads();
    b ^= 1;
  }

  // epilogue: pair even/odd n-frags (u, g) -> gelu(u)*g
#pragma unroll
  for (int m = 0; m < 4; ++m) {
#pragma unroll
    for (int p = 0; p < 2; ++p) {
      f32x4 u = acc[m][2 * p], g = acc[m][2 * p + 1];
      int hcol = (nt * 4 + wn * 2 + p) * 16 + fr;
#pragma unroll
      for (int j = 0; j < 4; ++j) {
        int sl = mt * 128 + wm * 64 + m * 16 + q4r * 4 + j;
        float hv = (sl < cnt) ? gelu_fast(u[j]) * g[j] : 0.f;
        hbuf[(size_t)(hb + sl) * HDIM + hcol] = f2bf(hv);
      }
    }
  }
}

// ============ down GEMM: 256x256, 4-phase counted-vmcnt pipeline ==========
__global__ __launch_bounds__(512) void gemm_down8(
    const unsigned short* __restrict__ hbuf, const short* __restrict__ wd,
    const int* __restrict__ base,
    const int* __restrict__ work, const int* __restrict__ nwork,
    unsigned short* __restrict__ yb) {
  int y = blockIdx.y;
  if (y >= *nwork) return;
  int wk = work[y];
  int e = wk >> 8, mt = wk & 255, nt = blockIdx.x;
  int hb = base[e];
  const short* wdE = wd + (size_t)e * 2097152;

  __shared__ short lds[65536];

  int tid = threadIdx.x, lane = tid & 63, wid = tid >> 6;
  int wm = wid >> 2, wn = wid & 3;
  int fr = lane & 15, q4r = lane >> 4;

  size_t aOff[2];
#pragma unroll
  for (int c = 0; c < 2; ++c)
    aOff[c] = (size_t)(hb + mt * 256 + (c * 8 + wid) * 16 + fr) * HDIM + q4r * 8;
  size_t bOff[2];
#pragma unroll
  for (int c = 0; c < 2; ++c)
    bOff[c] = ((size_t)(nt * 16 + c * 8 + wid) * 64) * 512 + lane * 8;

#define DWN_STAGE_A(tt, k32)                                                   \
  { int bb_ = ((tt) & 1) * 32768;                                              \
    gload16(hbuf + aOff[0] + (tt) * 64 + (k32) * 32,                           \
            &lds[bb_ + ((k32) * 16 + wid) * 512 + lane * 8]);                  \
    gload16(hbuf + aOff[1] + (tt) * 64 + (k32) * 32,                           \
            &lds[bb_ + ((k32) * 16 + 8 + wid) * 512 + lane * 8]); }
#define DWN_STAGE_B(tt, k32)                                                   \
  { int bb_ = ((tt) & 1) * 32768;                                              \
    gload16(wdE + bOff[0] + (size_t)((tt) * 2 + (k32)) * 512,                  \
            &lds[bb_ + 16384 + ((k32) * 16 + wid) * 512 + lane * 8]);          \
    gload16(wdE + bOff[1] + (size_t)((tt) * 2 + (k32)) * 512,                  \
            &lds[bb_ + 16384 + ((k32) * 16 + 8 + wid) * 512 + lane * 8]); }
#define DWN_READA(k32, mh)                                                     \
  { _Pragma("unroll") for (int i = 0; i < 4; ++i)                              \
      af[i] = *(const bf16x8*)&lds[bb + ((k32) * 16 + wm * 8 + (mh) * 4 + i) * \
                                       512 + lane * 8]; }
#define DWN_READB(k32)                                                         \
  { _Pragma("unroll") for (int n = 0; n < 4; ++n)                              \
      bf[n] = *(const bf16x8*)&lds[bb + 16384 + ((k32) * 16 + wn * 4 + n) *    \
                                       512 + lane * 8]; }
#define DWN_MFMA(mh)                                                           \
  { __builtin_amdgcn_s_setprio(1);                                             \
    _Pragma("unroll") for (int i = 0; i < 4; ++i)                              \
      _Pragma("unroll") for (int n = 0; n < 4; ++n)                            \
        acc[(mh) * 4 + i][n] = __builtin_amdgcn_mfma_f32_16x16x32_bf16(        \
            af[i], bf[n], acc[(mh) * 4 + i][n], 0, 0, 0);                      \
    __builtin_amdgcn_s_setprio(0); }

  f32x4 acc[8][4] = {};
  bf16x8 af[4], bf[4];

  DWN_STAGE_A(0, 0); DWN_STAGE_B(0, 0); DWN_STAGE_A(0, 1); DWN_STAGE_B(0, 1);
  WAITVM(4); BARX();

#pragma unroll 1
  for (int t = 0; t < 31; ++t) {
    const int bb = (t & 1) * 32768;
    DWN_READA(0, 0); DWN_READB(0); DWN_STAGE_A(t + 1, 0);
    BARX(); DWN_MFMA(0); BARX();
    DWN_READA(0, 1); DWN_STAGE_B(t + 1, 0);
    BARX(); DWN_MFMA(1); WAITVM(4); BARX();
    DWN_READA(1, 0); DWN_READB(1); DWN_STAGE_A(t + 1, 1);
    BARX(); DWN_MFMA(0); BARX();
    DWN_READA(1, 1); DWN_STAGE_B(t + 1, 1);
    BARX(); DWN_MFMA(1); WAITVM(4); BARX();
  }
  {  // t = 31
    const int bb = 32768;
    DWN_READA(0, 0); DWN_READB(0); BARX(); DWN_MFMA(0); BARX();
    DWN_READA(0, 1); BARX(); DWN_MFMA(1); WAITVM(0); BARX();
    DWN_READA(1, 0); DWN_READB(1); BARX(); DWN_MFMA(0); BARX();
    DWN_READA(1, 1); DWN_MFMA(1);
  }

#pragma unroll
  for (int m = 0; m < 8; ++m) {
#pragma unroll
    for (int n = 0; n < 4; ++n) {
      int col = (nt * 16 + wn * 4 + n) * 16 + fr;
      f32x4 a = acc[m][n];
#pragma unroll
      for (int j = 0; j < 4; ++j) {
        int row = mt * 256 + wm * 128 + m * 16 + q4r * 4 + j;
        yb[(size_t)(hb + row) * DMODEL + col] = f2bf(a[j]);
      }
    }
  }
}

// ------------ gather: out[t] = w0*y[p0] + w1*y[p1] + y[shared+t] ------------
__global__ __launch_bounds__(256) void gather_kernel(
    const unsigned short* __restrict__ yb, const int* __restrict__ tokpos,
    const float* __restrict__ wtok, const int* __restrict__ base,
    float* __restrict__ out) {
  int t = blockIdx.x, c4 = threadIdx.x;
  int p0 = tokpos[2 * t], p1 = tokpos[2 * t + 1];
  float w0 = wtok[2 * t], w1 = wtok[2 * t + 1];
  size_t r0 = (size_t)(base[p0 >> 12] + (p0 & 4095)) * DMODEL;
  size_t r1 = (size_t)(base[p1 >> 12] + (p1 & 4095)) * DMODEL;
  size_t rs = (size_t)(base[8] + t) * DMODEL;
  ushort4 v0 = *(const ushort4*)(yb + r0 + c4 * 4);
  ushort4 v1 = *(const ushort4*)(yb + r1 + c4 * 4);
  ushort4 vs = *(const ushort4*)(yb + rs + c4 * 4);
  float4 o;
  o.x = w0 * bf2f(v0.x) + w1 * bf2f(v1.x) + bf2f(vs.x);
  o.y = w0 * bf2f(v0.y) + w1 * bf2f(v1.y) + bf2f(vs.y);
  o.z = w0 * bf2f(v0.z) + w1 * bf2f(v1.z) + bf2f(vs.z);
  o.w = w0 * bf2f(v0.w) + w1 * bf2f(v1.w) + bf2f(vs.w);
  *(float4*)(out + (size_t)t * DMODEL + c4 * 4) = o;
}

extern "C" void kernel_launch(void* const* d_in, const int* in_sizes, int n_in,
                              void* d_out, int out_size, void* d_ws, size_t ws_size,
                              hipStream_t stream) {
  const float* x   = (const float*)d_in[0];
  const float* Wr  = (const float*)d_in[1];
  const float* w1  = (const float*)d_in[2];
  const float* w2  = (const float*)d_in[3];
  const float* w3  = (const float*)d_in[4];
  const float* w1s = (const float*)d_in[5];
  const float* w2s = (const float*)d_in[6];
  const float* w3s = (const float*)d_in[7];
  float* out = (float*)d_out;

  char* ws = (char*)d_ws;
  const size_t HBUF_OFF = 0;                        // 14336*2048 bf16 = 58.7 MB
  const size_t XB_OFF   = 58720256;                 // 4096*1024 bf16
  const size_t WB_OFF   = XB_OFF + 8388608;         // 9*4M shorts = 75.5 MB
  const size_t WD_OFF   = WB_OFF + 75497472;        // 9*2M shorts = 37.7 MB
  const size_t PERM_OFF = WD_OFF + 37748736;        // 8*4096 int
  const size_t TP_OFF   = PERM_OFF + 131072;        // 8192 int
  const size_t WT_OFF   = TP_OFF + 32768;           // 8192 float
  const size_t CTRL_OFF = WT_OFF + 32768;           // 256 B
  const size_t W128_OFF = CTRL_OFF + 256;           // 128 ints
  const size_t W256_OFF = W128_OFF + 512;           // 64 ints

  unsigned short* hbuf = (unsigned short*)(ws + HBUF_OFF);
  short* xb = (short*)(ws + XB_OFF);
  short* wB = (short*)(ws + WB_OFF);
  short* wd = (short*)(ws + WD_OFF);
  unsigned short* yb = (unsigned short*)(ws + WB_OFF);  // overlays wB (dead after upgate)
  int*   perm   = (int*)(ws + PERM_OFF);
  int*   tokpos = (int*)(ws + TP_OFF);
  float* wtok   = (float*)(ws + WT_OFF);
  int*   cursor = (int*)(ws + CTRL_OFF);
  int*   cnt1   = (int*)(ws + CTRL_OFF + 64);
  float* psum   = (float*)(ws + CTRL_OFF + 128);
  int*   base   = (int*)(ws + CTRL_OFF + 192);
  int*   n128   = (int*)(ws + CTRL_OFF + 236);
  int*   n256   = (int*)(ws + CTRL_OFF + 240);
  int*   work128 = (int*)(ws + W128_OFF);
  int*   work256 = (int*)(ws + W256_OFF);

  hipMemsetAsync(ws + CTRL_OFF, 0, 256, stream);

  prep1_kernel<<<19456, 256, 0, stream>>>(x, Wr, w1, w3, w1s, w3s, wB,
                                          cursor, cnt1, psum, perm,
                                          tokpos, wtok, xb);
  finalize_kernel<<<1, 64, 0, stream>>>(cursor, cnt1, psum, base,
                                        work128, n128, work256, n256,
                                        out + (size_t)T_TOK * DMODEL);
  gemm_upgate_f<<<12544, 256, 0, stream>>>(xb, wB, w2, w2s, wd,
                                           cursor, base, work128, n128,
                                           perm, hbuf);
  gemm_down8<<<dim3(4, 64), 512, 0, stream>>>(hbuf, wd, base, work256, n256, yb);
  gather_kernel<<<4096, 256, 0, stream>>>(yb, tokpos, wtok, base, out);
}